// Round 1
// baseline (4538.732 us; speedup 1.0000x reference)
//
#include <hip/hip_runtime.h>
#include <stdint.h>

// Problem dims (fixed by reference setup_inputs)
#define DD 64
#define HH 128
#define WW 128
#define NVOX (DD * HH * WW)   // 1048576 = 1<<20
#define BATCH 2
#define NCLS 4
#define NMASK 12              // 6 pred masks then 6 target masks

// ---------------- lock-free union-find ----------------
// union-by-min root + path halving. Races are benign: parent pointers only
// ever move toward smaller-indexed ancestors; CAS-linking only links roots.

__device__ __forceinline__ int uf_find(int* P, int x) {
    while (true) {
        int p = P[x];
        if (p == x) return x;
        int gp = P[p];
        if (gp != p) P[x] = gp;   // path halving (benign race)
        x = gp;
    }
}

__device__ __forceinline__ void uf_union(int* P, int a, int b) {
    while (true) {
        a = uf_find(P, a);
        b = uf_find(P, b);
        if (a == b) return;
        int lo = a < b ? a : b;
        int hi = a < b ? b : a;
        int old = atomicCAS(&P[hi], hi, lo);
        if (old == hi) return;    // linked hi -> lo
        a = lo; b = old;          // hi was already linked; retry
    }
}

// active predicate per phase: 0 = mask CC, 1 = eroded-mask CC, 2 = background
__device__ __forceinline__ bool is_active(const uint8_t* __restrict__ m, int i,
                                          int z, int y, int x, int phase) {
    if (phase == 0) return m[i] != 0;
    if (phase == 2) return m[i] == 0;
    // phase 1: binary erosion, 6-conn, border_value = 0 (border voxels never survive)
    if (!m[i]) return false;
    if (z == 0 || z == DD - 1 || y == 0 || y == HH - 1 || x == 0 || x == WW - 1)
        return false;
    return m[i - HH * WW] && m[i + HH * WW] &&
           m[i - WW]      && m[i + WW]      &&
           m[i - 1]       && m[i + 1];
}

// ---------------- kernels ----------------

// Build all 12 masks; zero the 12x4 counter block.
__global__ void k_masks(const float* __restrict__ pred, const int* __restrict__ tgt,
                        uint8_t* __restrict__ masks, int* __restrict__ counts) {
    int tid = blockIdx.x * blockDim.x + threadIdx.x;   // 0 .. BATCH*NVOX-1
    if (tid < NMASK * 4) counts[tid] = 0;
    int b = tid >> 20;
    int i = tid & (NVOX - 1);
    const float* p = pred + (size_t)b * NCLS * NVOX + i;
    float x0 = p[0], x1 = p[NVOX], x2 = p[2 * NVOX], x3 = p[3 * NVOX];
    float mx = fmaxf(fmaxf(x0, x1), fmaxf(x2, x3));
    float e0 = expf(x0 - mx), e1 = expf(x1 - mx), e2 = expf(x2 - mx), e3 = expf(x3 - mx);
    float S = e0 + e1 + e2 + e3;
    masks[(size_t)(b * 3 + 0) * NVOX + i] = (e1 / S > 0.5f);
    masks[(size_t)(b * 3 + 1) * NVOX + i] = (e2 / S > 0.5f);
    masks[(size_t)(b * 3 + 2) * NVOX + i] = (e3 / S > 0.5f);
    int t = tgt[(size_t)b * NVOX + i];
    masks[(size_t)(6 + b * 3 + 0) * NVOX + i] = (t == 1);
    masks[(size_t)(6 + b * 3 + 1) * NVOX + i] = (t == 2);
    masks[(size_t)(6 + b * 3 + 2) * NVOX + i] = (t == 3);
}

// parent[i] = i for i in [0, NVOX]  (NVOX is the virtual border node)
__global__ void k_init(int* __restrict__ parent) {
    int idx = blockIdx.x * blockDim.x + threadIdx.x;
    if (idx > NVOX) return;
    parent[(size_t)blockIdx.y * (NVOX + 1) + idx] = idx;
}

__global__ void k_merge(const uint8_t* __restrict__ masks, int* __restrict__ parent,
                        int phase, int m0) {
    int i = blockIdx.x * blockDim.x + threadIdx.x;          // NVOX divisible by 256
    const uint8_t* msk = masks + (size_t)(m0 + blockIdx.y) * NVOX;
    int* P = parent + (size_t)blockIdx.y * (NVOX + 1);
    int z = i >> 14, r = i & 16383, y = r >> 7, x = r & 127;
    if (!is_active(msk, i, z, y, x, phase)) return;
    if (x + 1 < WW && is_active(msk, i + 1, z, y, x + 1, phase))        uf_union(P, i, i + 1);
    if (y + 1 < HH && is_active(msk, i + WW, z, y + 1, x, phase))       uf_union(P, i, i + WW);
    if (z + 1 < DD && is_active(msk, i + HH * WW, z + 1, y, x, phase))  uf_union(P, i, i + HH * WW);
    if (phase == 2 &&
        (z == 0 || z == DD - 1 || y == 0 || y == HH - 1 || x == 0 || x == WW - 1))
        uf_union(P, i, NVOX);   // border background -> virtual outside node
}

__global__ void k_count(const uint8_t* __restrict__ masks, int* __restrict__ parent,
                        int phase, int m0, int* __restrict__ counts) {
    __shared__ int sRootN;
    int i = blockIdx.x * blockDim.x + threadIdx.x;
    const uint8_t* msk = masks + (size_t)(m0 + blockIdx.y) * NVOX;
    int* P = parent + (size_t)blockIdx.y * (NVOX + 1);
    if (phase == 2 && threadIdx.x == 0) sRootN = uf_find(P, NVOX);
    if (phase == 2) __syncthreads();
    bool flag;
    int z = i >> 14, r = i & 16383, y = r >> 7, x = r & 127;
    if (phase < 2) {
        // roots of active voxels == number of components
        flag = is_active(msk, i, z, y, x, phase) && (P[i] == i);
    } else {
        // cavity voxel: background, not connected to the virtual border node
        flag = (msk[i] == 0) && (uf_find(P, i) != sRootN);
    }
    unsigned long long bal = __ballot(flag);
    if ((threadIdx.x & 63) == 0 && bal)
        atomicAdd(&counts[(m0 + blockIdx.y) * 4 + phase], (int)__popcll(bal));
}

__global__ void k_loss(const int* __restrict__ counts, float* __restrict__ out) {
    if (threadIdx.x != 0 || blockIdx.x != 0) return;
    float acc = 0.f;
    for (int m = 0; m < 6; ++m) {
        int pb0 = counts[m * 4 + 0], pbe = counts[m * 4 + 1], pcv = counts[m * 4 + 2];
        int tb0 = counts[(m + 6) * 4 + 0], tbe = counts[(m + 6) * 4 + 1], tcv = counts[(m + 6) * 4 + 2];
        int pb1 = max(0, pb0 - pbe), tb1 = max(0, tb0 - tbe);
        int pb2 = pcv / 100, tb2 = tcv / 100;
        acc += fabsf((float)(pb0 - tb0)) + fabsf((float)(pb1 - tb1)) + fabsf((float)(pb2 - tb2));
    }
    out[0] = 0.1f * acc / 6.0f;
}

// ---------------- launch ----------------

extern "C" void kernel_launch(void* const* d_in, const int* in_sizes, int n_in,
                              void* d_out, int out_size, void* d_ws, size_t ws_size,
                              hipStream_t stream) {
    const float* pred = (const float*)d_in[0];
    const int* tgt = (const int*)d_in[1];
    float* out = (float*)d_out;

    uint8_t* ws = (uint8_t*)d_ws;
    uint8_t* masks = ws;
    size_t off = ((size_t)NMASK * NVOX + 255) & ~(size_t)255;
    int* counts = (int*)(ws + off);
    off += 256;
    int* parent = (int*)(ws + off);

    // how many masks' parent arrays fit at once (chunk if ws is small)
    size_t avail = ws_size > off ? ws_size - off : 0;
    int PB = (int)(avail / ((size_t)(NVOX + 1) * sizeof(int)));
    if (PB > NMASK) PB = NMASK;
    if (PB < 1) PB = 1;   // assume ws is at least ~17 MB

    k_masks<<<dim3((BATCH * NVOX) / 256), 256, 0, stream>>>(pred, tgt, masks, counts);

    for (int phase = 0; phase < 3; ++phase) {
        for (int m0 = 0; m0 < NMASK; m0 += PB) {
            int mb = PB < (NMASK - m0) ? PB : (NMASK - m0);
            k_init<<<dim3((NVOX + 1 + 255) / 256, mb), 256, 0, stream>>>(parent);
            k_merge<<<dim3(NVOX / 256, mb), 256, 0, stream>>>(masks, parent, phase, m0);
            k_count<<<dim3(NVOX / 256, mb), 256, 0, stream>>>(masks, parent, phase, m0, counts);
        }
    }

    k_loss<<<1, 64, 0, stream>>>(counts, out);
}

// Round 2
// 1380.654 us; speedup vs baseline: 3.2874x; 3.2874x over previous
//
#include <hip/hip_runtime.h>
#include <stdint.h>

#define DD 64
#define HH 128
#define WW 128
#define NVOX (DD * HH * WW)      // 1<<20
#define NWRD (NVOX / 32)         // 32768 words per mask
#define BATCH 2
#define NCLS 4
#define NMASK 12                 // 6 pred then 6 target
#define NPROB 36                 // phase*12 + m ; phase: 0=mask 1=eroded 2=background
#define PSTRIDE (NVOX + 64)      // ints per parent slot (includes virtual node NVOX)

// ---------------- lock-free union-find ----------------
__device__ __forceinline__ int uf_find(int* P, int x) {
    while (true) {
        int p = P[x];
        if (p == x) return x;
        int gp = P[p];
        if (gp != p) P[x] = gp;   // path halving (benign race)
        x = gp;
    }
}
__device__ __forceinline__ int uf_find_ro(const int* P, int x) {
    int p;
    while ((p = P[x]) != x) x = p;
    return x;
}
__device__ __forceinline__ void uf_union(int* P, int a, int b) {
    while (true) {
        a = uf_find(P, a);
        b = uf_find(P, b);
        if (a == b) return;
        int lo = a < b ? a : b;
        int hi = a < b ? b : a;
        int old = atomicCAS(&P[hi], hi, lo);
        if (old == hi) return;
        a = lo; b = old;
    }
}

// word loader for problem (phase, m)
__device__ __forceinline__ uint32_t ld_word(const uint32_t* __restrict__ maskW,
                                            const uint32_t* __restrict__ erodW,
                                            int phase, int m, int w) {
    if (phase == 0) return maskW[m * NWRD + w];
    if (phase == 1) return erodW[m * NWRD + w];
    return ~maskW[m * NWRD + w];
}

// ---------------- kernels ----------------

// Build 12 bitpacked masks via ballot; zero counters.
__global__ void k_masks(const float* __restrict__ pred, const int* __restrict__ tgt,
                        uint32_t* __restrict__ maskW, int* __restrict__ counts) {
    int tid = blockIdx.x * blockDim.x + threadIdx.x;   // 0 .. BATCH*NVOX-1
    if (tid < 64) counts[tid] = 0;
    int b = tid >> 20;
    int i = tid & (NVOX - 1);
    const float* p = pred + (size_t)b * NCLS * NVOX + i;
    float x0 = p[0], x1 = p[NVOX], x2 = p[2 * NVOX], x3 = p[3 * NVOX];
    float mx = fmaxf(fmaxf(x0, x1), fmaxf(x2, x3));
    float e0 = __expf(x0 - mx), e1 = __expf(x1 - mx), e2 = __expf(x2 - mx), e3 = __expf(x3 - mx);
    float S = e0 + e1 + e2 + e3;
    int t = tgt[(size_t)b * NVOX + i];
    bool f[12];
    f[b * 3 + 0] = (e1 / S > 0.5f);
    f[b * 3 + 1] = (e2 / S > 0.5f);
    f[b * 3 + 2] = (e3 / S > 0.5f);
    f[3 - b * 3 + 0] = false; f[3 - b * 3 + 1] = false; f[3 - b * 3 + 2] = false;
    for (int c = 0; c < 3; ++c) {
        f[6 + b * 3 + c] = (t == c + 1);
        f[6 + (3 - b * 3) + c] = false;
    }
    int lane = threadIdx.x & 63;
    int wbase = i >> 5;                       // low word for this wave's lane0..31
    for (int m = 0; m < 12; ++m) {
        unsigned long long bal = __ballot(f[m]);
        if (lane == 0)  maskW[m * NWRD + wbase] = (uint32_t)bal;
        if (lane == 32) maskW[m * NWRD + wbase] = (uint32_t)(bal >> 32);
    }
}

// wait: masks for the other batch half must not be overwritten with zeros.
// (handled above by ballot of 'false' writing 0 into the other half's words?
//  NO — each wave only writes the words covering ITS voxels; f[other-half]
//  ballots would write zeros into THIS wave's word range of the other mask.
//  We avoid that by only writing masks belonging to this b.)
// -> corrected in k_masks2 below; k_masks is not launched.

__global__ void k_masks2(const float* __restrict__ pred, const int* __restrict__ tgt,
                         uint32_t* __restrict__ maskW, int* __restrict__ counts) {
    int tid = blockIdx.x * blockDim.x + threadIdx.x;   // 0 .. BATCH*NVOX-1
    if (tid < 64) counts[tid] = 0;
    int b = tid >> 20;
    int i = tid & (NVOX - 1);
    const float* p = pred + (size_t)b * NCLS * NVOX + i;
    float x0 = p[0], x1 = p[NVOX], x2 = p[2 * NVOX], x3 = p[3 * NVOX];
    float mx = fmaxf(fmaxf(x0, x1), fmaxf(x2, x3));
    float e0 = __expf(x0 - mx), e1 = __expf(x1 - mx), e2 = __expf(x2 - mx), e3 = __expf(x3 - mx);
    float S = e0 + e1 + e2 + e3;
    int t = tgt[(size_t)b * NVOX + i];
    int lane = threadIdx.x & 63;
    int wbase = i >> 5;
    float ev[3] = {e1, e2, e3};
    for (int c = 0; c < 3; ++c) {
        unsigned long long bal = __ballot(ev[c] / S > 0.5f);
        uint32_t* M = maskW + (size_t)(b * 3 + c) * NWRD;
        if (lane == 0)  M[wbase] = (uint32_t)bal;
        if (lane == 32) M[wbase] = (uint32_t)(bal >> 32);
        unsigned long long balT = __ballot(t == c + 1);
        uint32_t* MT = maskW + (size_t)(6 + b * 3 + c) * NWRD;
        if (lane == 0)  MT[wbase] = (uint32_t)balT;
        if (lane == 32) MT[wbase] = (uint32_t)(balT >> 32);
    }
}

// 6-conn binary erosion, border_value=0, bitwise.
__global__ void k_erode(const uint32_t* __restrict__ maskW, uint32_t* __restrict__ erodW) {
    int tid = blockIdx.x * blockDim.x + threadIdx.x;   // 0 .. 12*NWRD-1
    int m = tid / NWRD;
    int w = tid - m * NWRD;
    const uint32_t* M = maskW + (size_t)m * NWRD;
    int z = w >> 9, y = (w >> 2) & 127, q = w & 3;
    uint32_t a = M[w];
    uint32_t xl = (a << 1) | (q ? (M[w - 1] >> 31) : 0u);
    uint32_t xr = (a >> 1) | (q < 3 ? (M[w + 1] << 31) : 0u);
    uint32_t ym = (y > 0)   ? M[w - 4]   : 0u;
    uint32_t yp = (y < 127) ? M[w + 4]   : 0u;
    uint32_t zm = (z > 0)   ? M[w - 512] : 0u;
    uint32_t zp = (z < 63)  ? M[w + 512] : 0u;
    erodW[tid] = a & xl & xr & ym & yp & zm & zp;
}

// parent init: each active voxel points at its x-run head. One thread per row.
__global__ void k_init(const uint32_t* __restrict__ maskW, const uint32_t* __restrict__ erodW,
                       int* __restrict__ parent, int m0) {
    int r = blockIdx.x * blockDim.x + threadIdx.x;     // 0 .. 8191 rows
    int pr = m0 + blockIdx.y;
    int phase = pr / 12, m = pr % 12;
    int* P = parent + (size_t)blockIdx.y * PSTRIDE;
    if (r == 0) P[NVOX] = NVOX;                        // virtual border node
    if (r >= DD * HH) return;
    int rowbase = r * WW;                              // global bit index of row start
    uint32_t R[4];
    for (int q = 0; q < 4; ++q) R[q] = ld_word(maskW, erodW, phase, m, r * 4 + q);
    int head = 0;
    bool prev = false;
    for (int q = 0; q < 4; ++q) {
        uint32_t wb = R[q];
        int base = rowbase + 32 * q;
        while (wb) {
            int p = __ffs(wb) - 1;
            uint32_t run = wb >> p;
            uint32_t inv = ~run;
            int len = inv ? (__ffs(inv) - 1) : (32 - p);
            int start = (p == 0 && prev) ? head : (base + p);
            for (int j = 0; j < len; ++j) P[base + p + j] = start;
            head = start;
            if (p + len >= 32) break;
            wb &= ~(((1u << len) - 1u) << p);
        }
        prev = (R[q] >> 31) & 1u;
    }
}

// run-based y/z unions (+ border->virtual for phase 2). One thread per word.
__global__ void k_merge(const uint32_t* __restrict__ maskW, const uint32_t* __restrict__ erodW,
                        int* __restrict__ parent, int m0) {
    int w = blockIdx.x * blockDim.x + threadIdx.x;     // 0 .. NWRD-1
    int pr = m0 + blockIdx.y;
    int phase = pr / 12, m = pr % 12;
    int* P = parent + (size_t)blockIdx.y * PSTRIDE;
    int z = w >> 9, y = (w >> 2) & 127, q = w & 3;
    uint32_t a = ld_word(maskW, erodW, phase, m, w);
    if (!a) return;
    uint32_t aprev = q ? ld_word(maskW, erodW, phase, m, w - 1) : 0u;
    int i0 = w << 5;
    if (y < 127) {
        uint32_t by = ld_word(maskW, erodW, phase, m, w + 4);
        uint32_t ov = a & by;
        if (ov) {
            uint32_t bp = q ? ld_word(maskW, erodW, phase, m, w + 3) : 0u;
            uint32_t carry = (aprev & bp) >> 31;
            uint32_t st = ov & ~((ov << 1) | carry);
            while (st) {
                int p = __ffs(st) - 1; st &= st - 1;
                uf_union(P, i0 + p, i0 + p + WW);
            }
        }
    }
    if (z < 63) {
        uint32_t bz = ld_word(maskW, erodW, phase, m, w + 512);
        uint32_t ov = a & bz;
        if (ov) {
            uint32_t bp = q ? ld_word(maskW, erodW, phase, m, w + 511) : 0u;
            uint32_t carry = (aprev & bp) >> 31;
            uint32_t st = ov & ~((ov << 1) | carry);
            while (st) {
                int p = __ffs(st) - 1; st &= st - 1;
                uf_union(P, i0 + p, i0 + p + HH * WW);
            }
        }
    }
    if (phase == 2) {
        bool borderRow = (z == 0 || z == 63 || y == 0 || y == 127);
        if (borderRow) {
            uint32_t carry = aprev >> 31;
            uint32_t st = a & ~((a << 1) | carry);
            while (st) {
                int p = __ffs(st) - 1; st &= st - 1;
                uf_union(P, i0 + p, NVOX);
            }
        } else {
            if (q == 0 && (a & 1u)) uf_union(P, i0, NVOX);
            if (q == 3 && (a >> 31)) uf_union(P, i0 + 31, NVOX);
        }
    }
}

// count roots (phases 0/1) or cavity volume (phase 2). One thread per word.
__global__ void k_count(const uint32_t* __restrict__ maskW, const uint32_t* __restrict__ erodW,
                        int* __restrict__ parent, int m0, int* __restrict__ counts) {
    __shared__ int sRootN;
    int w = blockIdx.x * blockDim.x + threadIdx.x;
    int pr = m0 + blockIdx.y;
    int phase = pr / 12, m = pr % 12;
    int* P = parent + (size_t)blockIdx.y * PSTRIDE;
    if (phase == 2 && threadIdx.x == 0) sRootN = uf_find_ro(P, NVOX);
    if (phase == 2) __syncthreads();
    uint32_t a = ld_word(maskW, erodW, phase, m, w);
    int cnt = 0;
    if (a) {
        int i0 = w << 5;
        uint32_t st = a & ~(a << 1);          // word-local segment starts
        if (phase < 2) {
            while (st) {
                int p = __ffs(st) - 1; st &= st - 1;
                cnt += (P[i0 + p] == i0 + p);  // only run heads can be roots
            }
        } else {
            int rootN = sRootN;
            while (st) {
                int p = __ffs(st) - 1; st &= st - 1;
                uint32_t run = a >> p;
                uint32_t inv = ~run;
                int len = inv ? (__ffs(inv) - 1) : (32 - p);
                if (uf_find_ro(P, i0 + p) != rootN) cnt += len;
            }
        }
    }
    for (int off = 32; off; off >>= 1) cnt += __shfl_down(cnt, off);
    if ((threadIdx.x & 63) == 0 && cnt) atomicAdd(&counts[pr], cnt);
}

__global__ void k_loss(const int* __restrict__ counts, float* __restrict__ out) {
    if (threadIdx.x != 0 || blockIdx.x != 0) return;
    float acc = 0.f;
    for (int m = 0; m < 6; ++m) {
        int pb0 = counts[m],      pbe = counts[12 + m],      pcv = counts[24 + m];
        int tb0 = counts[6 + m],  tbe = counts[12 + 6 + m],  tcv = counts[24 + 6 + m];
        int pb1 = max(0, pb0 - pbe), tb1 = max(0, tb0 - tbe);
        int pb2 = pcv / 100, tb2 = tcv / 100;
        acc += fabsf((float)(pb0 - tb0)) + fabsf((float)(pb1 - tb1)) + fabsf((float)(pb2 - tb2));
    }
    out[0] = 0.1f * acc / 6.0f;
}

// ---------------- launch ----------------
extern "C" void kernel_launch(void* const* d_in, const int* in_sizes, int n_in,
                              void* d_out, int out_size, void* d_ws, size_t ws_size,
                              hipStream_t stream) {
    const float* pred = (const float*)d_in[0];
    const int* tgt = (const int*)d_in[1];
    float* out = (float*)d_out;

    uint8_t* ws = (uint8_t*)d_ws;
    uint32_t* maskW = (uint32_t*)ws;
    size_t off = (size_t)NMASK * NWRD * 4;                 // 1.5 MB
    uint32_t* erodW = (uint32_t*)(ws + off);
    off += (size_t)NMASK * NWRD * 4;                       // +1.5 MB
    int* counts = (int*)(ws + off);
    off += 256;
    off = (off + 255) & ~(size_t)255;
    int* parent = (int*)(ws + off);

    size_t avail = ws_size > off ? ws_size - off : 0;
    int PB = (int)(avail / ((size_t)PSTRIDE * sizeof(int)));
    if (PB > NPROB) PB = NPROB;
    if (PB < 1) PB = 1;

    k_masks2<<<dim3((BATCH * NVOX) / 256), 256, 0, stream>>>(pred, tgt, maskW, counts);
    k_erode<<<dim3((NMASK * NWRD) / 256), 256, 0, stream>>>(maskW, erodW);

    for (int m0 = 0; m0 < NPROB; m0 += PB) {
        int mb = PB < (NPROB - m0) ? PB : (NPROB - m0);
        k_init <<<dim3((DD * HH) / 256, mb), 256, 0, stream>>>(maskW, erodW, parent, m0);
        k_merge<<<dim3(NWRD / 256, mb), 256, 0, stream>>>(maskW, erodW, parent, m0);
        k_count<<<dim3(NWRD / 256, mb), 256, 0, stream>>>(maskW, erodW, parent, m0, counts);
    }

    k_loss<<<1, 64, 0, stream>>>(counts, out);
}

// Round 3
// 457.651 us; speedup vs baseline: 9.9175x; 3.0168x over previous
//
#include <hip/hip_runtime.h>
#include <stdint.h>

#define DD 64
#define HH 128
#define WW 128
#define NVOX (DD * HH * WW)      // 1<<20
#define NWRD (NVOX / 32)         // 32768 words per mask
#define BATCH 2
#define NCLS 4
#define NMASK 12                 // 6 pred then 6 target
#define NPROB 36                 // phase*12 + m ; phase: 0=mask 1=eroded 2=background
#define PSTRIDE (NVOX + 64)      // ints per parent slot (includes virtual node NVOX)
#define NTILE 128                // (HH/8)*(DD/8) tiles of 128x8x8 voxels

// ---------------- global lock-free union-find ----------------
__device__ __forceinline__ int uf_find(int* P, int x) {
    while (true) {
        int p = P[x];
        if (p == x) return x;
        int gp = P[p];
        if (gp != p) P[x] = gp;   // path halving (benign race)
        x = gp;
    }
}
__device__ __forceinline__ int uf_find_ro(const int* P, int x) {
    int p;
    while ((p = P[x]) != x) x = p;
    return x;
}
__device__ __forceinline__ void uf_union(int* P, int a, int b) {
    while (true) {
        a = uf_find(P, a);
        b = uf_find(P, b);
        if (a == b) return;
        int lo = a < b ? a : b;
        int hi = a < b ? b : a;
        int old = atomicCAS(&P[hi], hi, lo);
        if (old == hi) return;
        a = lo; b = old;
    }
}

// ---------------- LDS union-find (swizzled index: bank-conflict-free) ----
#define SW(v) ((v) + ((v) >> 5))
__device__ __forceinline__ int lfind(int* lp, int x) {
    while (true) {
        int p = lp[SW(x)];
        if (p == x) return x;
        int gp = lp[SW(p)];
        if (gp != p) lp[SW(x)] = gp;
        x = gp;
    }
}
__device__ __forceinline__ void lunion(int* lp, int a, int b) {
    while (true) {
        a = lfind(lp, a);
        b = lfind(lp, b);
        if (a == b) return;
        int lo = a < b ? a : b;
        int hi = a < b ? b : a;
        int old = atomicCAS(&lp[SW(hi)], hi, lo);
        if (old == hi) return;
        a = lo; b = old;
    }
}

// word loader for problem (phase, m)
__device__ __forceinline__ uint32_t ld_word(const uint32_t* __restrict__ maskW,
                                            const uint32_t* __restrict__ erodW,
                                            int phase, int m, int w) {
    if (phase == 0) return maskW[m * NWRD + w];
    if (phase == 1) return erodW[m * NWRD + w];
    return ~maskW[m * NWRD + w];
}

// local voxel idx -> global voxel idx for tile (ty, tz)
__device__ __forceinline__ int l2g(int l, int ty, int tz) {
    int rw = l >> 5, rb = l & 31;
    int rq = rw & 3, ryl = (rw >> 2) & 7, rzl = rw >> 5;
    int rgw = ((tz * 8 + rzl) * 128 + (ty * 8 + ryl)) * 4 + rq;
    return (rgw << 5) + rb;
}

// ---------------- kernels ----------------

// Build 12 bitpacked masks via ballot; zero counters.
__global__ void k_masks2(const float* __restrict__ pred, const int* __restrict__ tgt,
                         uint32_t* __restrict__ maskW, int* __restrict__ counts) {
    int tid = blockIdx.x * blockDim.x + threadIdx.x;   // 0 .. BATCH*NVOX-1
    if (tid < 64) counts[tid] = 0;
    int b = tid >> 20;
    int i = tid & (NVOX - 1);
    const float* p = pred + (size_t)b * NCLS * NVOX + i;
    float x0 = p[0], x1 = p[NVOX], x2 = p[2 * NVOX], x3 = p[3 * NVOX];
    float mx = fmaxf(fmaxf(x0, x1), fmaxf(x2, x3));
    float e0 = __expf(x0 - mx), e1 = __expf(x1 - mx), e2 = __expf(x2 - mx), e3 = __expf(x3 - mx);
    float S = e0 + e1 + e2 + e3;
    int t = tgt[(size_t)b * NVOX + i];
    int lane = threadIdx.x & 63;
    int wbase = i >> 5;
    float ev[3] = {e1, e2, e3};
    for (int c = 0; c < 3; ++c) {
        unsigned long long bal = __ballot(ev[c] / S > 0.5f);
        uint32_t* M = maskW + (size_t)(b * 3 + c) * NWRD;
        if (lane == 0)  M[wbase] = (uint32_t)bal;
        if (lane == 32) M[wbase] = (uint32_t)(bal >> 32);
        unsigned long long balT = __ballot(t == c + 1);
        uint32_t* MT = maskW + (size_t)(6 + b * 3 + c) * NWRD;
        if (lane == 0)  MT[wbase] = (uint32_t)balT;
        if (lane == 32) MT[wbase] = (uint32_t)(balT >> 32);
    }
}

// 6-conn binary erosion, border_value=0, bitwise.
__global__ void k_erode(const uint32_t* __restrict__ maskW, uint32_t* __restrict__ erodW) {
    int tid = blockIdx.x * blockDim.x + threadIdx.x;   // 0 .. 12*NWRD-1
    int m = tid / NWRD;
    int w = tid - m * NWRD;
    const uint32_t* M = maskW + (size_t)m * NWRD;
    int z = w >> 9, y = (w >> 2) & 127, q = w & 3;
    uint32_t a = M[w];
    uint32_t xl = (a << 1) | (q ? (M[w - 1] >> 31) : 0u);
    uint32_t xr = (a >> 1) | (q < 3 ? (M[w + 1] << 31) : 0u);
    uint32_t ym = (y > 0)   ? M[w - 4]   : 0u;
    uint32_t yp = (y < 127) ? M[w + 4]   : 0u;
    uint32_t zm = (z > 0)   ? M[w - 512] : 0u;
    uint32_t zp = (z < 63)  ? M[w + 512] : 0u;
    erodW[tid] = a & xl & xr & ym & yp & zm & zp;
}

// Tile-local CC (128x8x8 per block) in LDS; writes tile-resolved global parent.
__global__ void k_local(const uint32_t* __restrict__ maskW, const uint32_t* __restrict__ erodW,
                        int* __restrict__ parent, int m0) {
    __shared__ int lp[8192 + 256];   // swizzled 8192-entry parent
    int pr = m0 + blockIdx.y;
    int phase = pr / 12, m = pr % 12;
    int* P = parent + (size_t)blockIdx.y * PSTRIDE;
    int tile = blockIdx.x;                         // 0..127
    int tz = tile >> 4, ty = tile & 15;
    int wl = threadIdx.x;                          // local word 0..255
    int zl = wl >> 5, yl = (wl >> 2) & 7, q = wl & 3;
    int gw = ((tz * 8 + zl) * 128 + (ty * 8 + yl)) * 4 + q;
    uint32_t a = ld_word(maskW, erodW, phase, m, gw);
    if (blockIdx.x == 0 && wl == 0) P[NVOX] = NVOX;    // virtual border node

    // x-run-head init within own word
    int lbase = wl << 5;
    {
        uint32_t wb = a;
        while (wb) {
            int p = __ffs(wb) - 1;
            uint32_t run = wb >> p;
            uint32_t inv = ~run;
            int len = inv ? (__ffs(inv) - 1) : (32 - p);
            for (int j = 0; j < len; ++j) lp[SW(lbase + p + j)] = lbase + p;
            if (p + len >= 32) break;
            wb &= ~(((1u << len) - 1u) << p);
        }
    }
    __syncthreads();

    uint32_t aprev = q ? ld_word(maskW, erodW, phase, m, gw - 1) : 0u;
    if (a) {
        // x link across word boundary within row
        if (q && (a & 1u) && (aprev >> 31)) lunion(lp, lbase, lbase - 1);
        // y unions within tile (run-based)
        if (yl < 7) {
            uint32_t by = ld_word(maskW, erodW, phase, m, gw + 4);
            uint32_t ov = a & by;
            if (ov) {
                uint32_t bp = q ? ld_word(maskW, erodW, phase, m, gw + 3) : 0u;
                uint32_t carry = (aprev & bp) >> 31;
                uint32_t st = ov & ~((ov << 1) | carry);
                while (st) {
                    int p = __ffs(st) - 1; st &= st - 1;
                    lunion(lp, lbase + p, lbase + p + 128);
                }
            }
        }
        // z unions within tile
        if (zl < 7) {
            uint32_t bz = ld_word(maskW, erodW, phase, m, gw + 512);
            uint32_t ov = a & bz;
            if (ov) {
                uint32_t bp = q ? ld_word(maskW, erodW, phase, m, gw + 511) : 0u;
                uint32_t carry = (aprev & bp) >> 31;
                uint32_t st = ov & ~((ov << 1) | carry);
                while (st) {
                    int p = __ffs(st) - 1; st &= st - 1;
                    lunion(lp, lbase + p, lbase + p + 1024);
                }
            }
        }
    }
    __syncthreads();

    // resolve own word's runs to tile roots (store resolved root back into lp)
    {
        uint32_t wb = a;
        while (wb) {
            int p = __ffs(wb) - 1;
            uint32_t run = wb >> p;
            uint32_t inv = ~run;
            int len = inv ? (__ffs(inv) - 1) : (32 - p);
            int r = lfind(lp, lbase + p);
            for (int j = 0; j < len; ++j) lp[SW(lbase + p + j)] = r;
            if (p + len >= 32) break;
            wb &= ~(((1u << len) - 1u) << p);
        }
    }
    // write global parent, vectorized
    int gbase = gw << 5;
    int4* dst = (int4*)(P + gbase);
#pragma unroll
    for (int k = 0; k < 8; ++k) {
        int b0 = 4 * k;
        int4 v;
        v.x = ((a >> (b0 + 0)) & 1) ? l2g(lp[SW(lbase + b0 + 0)], ty, tz) : gbase + b0 + 0;
        v.y = ((a >> (b0 + 1)) & 1) ? l2g(lp[SW(lbase + b0 + 1)], ty, tz) : gbase + b0 + 1;
        v.z = ((a >> (b0 + 2)) & 1) ? l2g(lp[SW(lbase + b0 + 2)], ty, tz) : gbase + b0 + 2;
        v.w = ((a >> (b0 + 3)) & 1) ? l2g(lp[SW(lbase + b0 + 3)], ty, tz) : gbase + b0 + 3;
        dst[k] = v;
    }
}

// boundary merges: only tile faces + phase-2 volume border. One thread per word.
__global__ void k_bmerge(const uint32_t* __restrict__ maskW, const uint32_t* __restrict__ erodW,
                         int* __restrict__ parent, int m0) {
    int w = blockIdx.x * blockDim.x + threadIdx.x;     // 0 .. NWRD-1
    int pr = m0 + blockIdx.y;
    int phase = pr / 12, m = pr % 12;
    int* P = parent + (size_t)blockIdx.y * PSTRIDE;
    int z = w >> 9, y = (w >> 2) & 127, q = w & 3;
    uint32_t a = ld_word(maskW, erodW, phase, m, w);
    if (!a) return;
    uint32_t aprev = q ? ld_word(maskW, erodW, phase, m, w - 1) : 0u;
    int i0 = w << 5;
    if ((y & 7) == 7 && y < 127) {
        uint32_t by = ld_word(maskW, erodW, phase, m, w + 4);
        uint32_t ov = a & by;
        if (ov) {
            uint32_t bp = q ? ld_word(maskW, erodW, phase, m, w + 3) : 0u;
            uint32_t carry = (aprev & bp) >> 31;
            uint32_t st = ov & ~((ov << 1) | carry);
            while (st) {
                int p = __ffs(st) - 1; st &= st - 1;
                uf_union(P, i0 + p, i0 + p + WW);
            }
        }
    }
    if ((z & 7) == 7 && z < 63) {
        uint32_t bz = ld_word(maskW, erodW, phase, m, w + 512);
        uint32_t ov = a & bz;
        if (ov) {
            uint32_t bp = q ? ld_word(maskW, erodW, phase, m, w + 511) : 0u;
            uint32_t carry = (aprev & bp) >> 31;
            uint32_t st = ov & ~((ov << 1) | carry);
            while (st) {
                int p = __ffs(st) - 1; st &= st - 1;
                uf_union(P, i0 + p, i0 + p + HH * WW);
            }
        }
    }
    if (phase == 2) {
        bool borderRow = (z == 0 || z == 63 || y == 0 || y == 127);
        if (borderRow) {
            uint32_t carry = aprev >> 31;
            uint32_t st = a & ~((a << 1) | carry);
            while (st) {
                int p = __ffs(st) - 1; st &= st - 1;
                uf_union(P, i0 + p, NVOX);
            }
        } else {
            if (q == 0 && (a & 1u)) uf_union(P, i0, NVOX);
            if (q == 3 && (a >> 31)) uf_union(P, i0 + 31, NVOX);
        }
    }
}

// count roots (phases 0/1) or cavity volume (phase 2). One thread per word.
__global__ void k_count(const uint32_t* __restrict__ maskW, const uint32_t* __restrict__ erodW,
                        int* __restrict__ parent, int m0, int* __restrict__ counts) {
    __shared__ int sRootN;
    int w = blockIdx.x * blockDim.x + threadIdx.x;
    int pr = m0 + blockIdx.y;
    int phase = pr / 12, m = pr % 12;
    int* P = parent + (size_t)blockIdx.y * PSTRIDE;
    if (phase == 2 && threadIdx.x == 0) sRootN = uf_find_ro(P, NVOX);
    if (phase == 2) __syncthreads();
    uint32_t a = ld_word(maskW, erodW, phase, m, w);
    int cnt = 0;
    if (a) {
        int i0 = w << 5;
        uint32_t st = a & ~(a << 1);          // word-local segment starts
        if (phase < 2) {
            while (st) {
                int p = __ffs(st) - 1; st &= st - 1;
                cnt += (P[i0 + p] == i0 + p);  // only run heads can be roots
            }
        } else {
            int rootN = sRootN;
            while (st) {
                int p = __ffs(st) - 1; st &= st - 1;
                uint32_t run = a >> p;
                uint32_t inv = ~run;
                int len = inv ? (__ffs(inv) - 1) : (32 - p);
                if (uf_find_ro(P, i0 + p) != rootN) cnt += len;
            }
        }
    }
    for (int off = 32; off; off >>= 1) cnt += __shfl_down(cnt, off);
    if ((threadIdx.x & 63) == 0 && cnt) atomicAdd(&counts[pr], cnt);
}

__global__ void k_loss(const int* __restrict__ counts, float* __restrict__ out) {
    if (threadIdx.x != 0 || blockIdx.x != 0) return;
    float acc = 0.f;
    for (int m = 0; m < 6; ++m) {
        int pb0 = counts[m],      pbe = counts[12 + m],      pcv = counts[24 + m];
        int tb0 = counts[6 + m],  tbe = counts[12 + 6 + m],  tcv = counts[24 + 6 + m];
        int pb1 = max(0, pb0 - pbe), tb1 = max(0, tb0 - tbe);
        int pb2 = pcv / 100, tb2 = tcv / 100;
        acc += fabsf((float)(pb0 - tb0)) + fabsf((float)(pb1 - tb1)) + fabsf((float)(pb2 - tb2));
    }
    out[0] = 0.1f * acc / 6.0f;
}

// ---------------- launch ----------------
extern "C" void kernel_launch(void* const* d_in, const int* in_sizes, int n_in,
                              void* d_out, int out_size, void* d_ws, size_t ws_size,
                              hipStream_t stream) {
    const float* pred = (const float*)d_in[0];
    const int* tgt = (const int*)d_in[1];
    float* out = (float*)d_out;

    uint8_t* ws = (uint8_t*)d_ws;
    uint32_t* maskW = (uint32_t*)ws;
    size_t off = (size_t)NMASK * NWRD * 4;                 // 1.5 MB
    uint32_t* erodW = (uint32_t*)(ws + off);
    off += (size_t)NMASK * NWRD * 4;                       // +1.5 MB
    int* counts = (int*)(ws + off);
    off += 256;
    off = (off + 255) & ~(size_t)255;
    int* parent = (int*)(ws + off);

    size_t avail = ws_size > off ? ws_size - off : 0;
    int PB = (int)(avail / ((size_t)PSTRIDE * sizeof(int)));
    if (PB > NPROB) PB = NPROB;
    if (PB < 1) PB = 1;

    k_masks2<<<dim3((BATCH * NVOX) / 256), 256, 0, stream>>>(pred, tgt, maskW, counts);
    k_erode<<<dim3((NMASK * NWRD) / 256), 256, 0, stream>>>(maskW, erodW);

    for (int m0 = 0; m0 < NPROB; m0 += PB) {
        int mb = PB < (NPROB - m0) ? PB : (NPROB - m0);
        k_local <<<dim3(NTILE, mb), 256, 0, stream>>>(maskW, erodW, parent, m0);
        k_bmerge<<<dim3(NWRD / 256, mb), 256, 0, stream>>>(maskW, erodW, parent, m0);
        k_count <<<dim3(NWRD / 256, mb), 256, 0, stream>>>(maskW, erodW, parent, m0, counts);
    }

    k_loss<<<1, 64, 0, stream>>>(counts, out);
}